// Round 1
// baseline (232.852 us; speedup 1.0000x reference)
//
#include <hip/hip_runtime.h>

// Sort_Latent_Layer: per row of (4096, 8192) fp32, view as 512 packets of 16,
// stable-argsort packets by first element, emit packets in sorted order.
//
// One 256-thread block per row. Row staged in LDS (32 KB), bitonic sort of
// 512 (key,idx) pairs with index tie-break (stability), coalesced float4 I/O.

#define NPK 512       // packets per row
#define DIM 8192      // floats per row
#define NT  256       // threads per block

__global__ __launch_bounds__(NT, 4)
void sort_latent_kernel(const float* __restrict__ z, float* __restrict__ out) {
    __shared__ float4 row4[DIM / 4];   // 32 KB: the whole row
    __shared__ float  keys[NPK];       // 2 KB
    __shared__ int    idxs[NPK];       // 2 KB

    const int t = threadIdx.x;
    const size_t rowoff = (size_t)blockIdx.x * DIM;
    const float4* __restrict__ zin4 = (const float4*)(z + rowoff);
    float4* __restrict__ out4 = (float4*)(out + rowoff);

    // ---- Stage row into LDS, fully coalesced 16B/lane loads ----
#pragma unroll
    for (int i = 0; i < DIM / 4 / NT; ++i)
        row4[t + NT * i] = zin4[t + NT * i];
    __syncthreads();

    // ---- Extract keys (first float of each 16-float packet) ----
    const float* rowf = (const float*)row4;
    keys[t]      = rowf[t * 16];
    keys[t + NT] = rowf[(t + NT) * 16];
    idxs[t]      = t;
    idxs[t + NT] = t + NT;
    __syncthreads();

    // ---- Bitonic sort of 512 (key, idx) pairs, ascending ----
    // Tie-break on idx => stable, matching jnp.argsort semantics.
    // 256 comparators per step, each thread owns exactly one.
    for (int k = 2; k <= NPK; k <<= 1) {
        for (int j = k >> 1; j > 0; j >>= 1) {
            const int i = ((t & ~(j - 1)) << 1) | (t & (j - 1));
            const int p = i | j;                 // partner (bit j of i is 0)
            const bool up = ((i & k) == 0);      // ascending sub-sequence?
            const float ka = keys[i], kb = keys[p];
            const int   ia = idxs[i], ib = idxs[p];
            // (ka,ia) > (kb,ib) lexicographic; pairs are never equal (idx unique)
            const bool agtb = (ka > kb) || (ka == kb && ia > ib);
            if (agtb == up) {
                keys[i] = kb; keys[p] = ka;
                idxs[i] = ib; idxs[p] = ia;
            }
            __syncthreads();
        }
    }

    // ---- Gather packets from LDS in sorted order; coalesced stores ----
    // float4 slot o: dest packet o>>2, quarter o&3; src packet idxs[o>>2].
#pragma unroll
    for (int i = 0; i < DIM / 4 / NT; ++i) {
        const int o = t + NT * i;
        const int src = idxs[o >> 2];
        out4[o] = row4[(src << 2) | (o & 3)];
    }
}

extern "C" void kernel_launch(void* const* d_in, const int* in_sizes, int n_in,
                              void* d_out, int out_size, void* d_ws, size_t ws_size,
                              hipStream_t stream) {
    const float* z = (const float*)d_in[0];
    float* out = (float*)d_out;
    const int nrows = in_sizes[0] / DIM;   // 4096
    sort_latent_kernel<<<nrows, NT, 0, stream>>>(z, out);
}